// Round 5
// baseline (545.326 us; speedup 1.0000x reference)
//
#include <hip/hip_runtime.h>
#include <hip/hip_cooperative_groups.h>

namespace cg = cooperative_groups;

// PageRank R13. R12 post-mortem: k5a 242->95us (gather-FEED bound, confirmed);
// partition ~398us is now the target, with k3a+k3b ~270us (two passes of the
// same ring machinery, C-stream read twice) and k4_deg ~75us (62 blocks = 24%
// CU). R13: (a) FUSE k3a+k3b -> k3ab: one R+C read, both scatters; colp moves
// to the pacc region (dead until k5a overwrites); row pairs packed u32 =
// col(20b)|r_low[11:0] + u8 hi2 side-array (wrg u16->u8: -32MB traffic).
// (b) k4 -> k4a (124 blk, 2-sub u16 partials staged in dead `out` buffer) +
// k4b merge (4x CU coverage). k5 scatter decodes packed form (~2 VALU/edge).
// NEED shrinks 137.5 -> 121.6 MB. All ring/flush logic identical to proven
// R9-R12 code, just co-located.

static constexpr int   NN       = 1000000;
static constexpr int   NE       = 16000000;
static constexpr float ALPHA    = 0.85f;
static constexpr int   MAX_ITER = 100;
static constexpr float THRESH   = 1.0f;                      // float32(N)*1e-6
static constexpr float INV_N    = 1.0f / 1000000.0f;
static constexpr float TELEPORT = 0.15f * (1.0f / 1000000.0f);
static constexpr float SCALE    = 8796093022208.0f;          // 2^43
static constexpr float INVSCALE = 1.0f / 8796093022208.0f;

static constexpr int T     = 256;
static constexpr int T5    = 512;            // k5a block size
static constexpr int NCH   = 2048;           // partition chunks (=K1/K3 grids)
static constexpr int BSH   = 14;
static constexpr int BKN   = 16384;          // nodes per bucket
static constexpr int NBK   = 64;             // buckets (62 used)
static constexpr int NBKU  = 62;             // used buckets
static constexpr int NSUBB = 496;            // 62 x 8 SpMV partials
static constexpr int NSLC  = 489;            // 2048-node merge slices
static constexpr int NK4A  = 124;            // 62 x 2 deg partials

// ws layout (bytes); colp overlays pacc (dead before K5a writes pacc)
static constexpr size_t OFF_WCG  = 0;                  // (NE+512) u32 packed col|rlow12
static constexpr size_t OFF_WR8  = 64002048;           // (NE+512) u8  rlow hi2
static constexpr size_t OFF_PACC = 80002560;           // 496*16384 i32 (colp u16 overlay)
static constexpr size_t OFF_CNTR = 112508416;          // 64*2048 u32
static constexpr size_t OFF_CNTC = 113032704;          // 64*2048 u32
static constexpr size_t OFF_CTRL = 113556992;          // 4KB
static constexpr size_t OFF_RDEG = 113561088;          // 4,000,000
static constexpr size_t OFF_W    = 117561088;          // 4,000,032 (w[NN]=0)
static constexpr size_t NEED     = 121561120;

typedef int      vi4 __attribute__((ext_vector_type(4)));
typedef unsigned vu4 __attribute__((ext_vector_type(4)));

template<typename TT>
__device__ __forceinline__ TT ntload(const TT* p) { return __builtin_nontemporal_load(p); }

struct P {
    unsigned* wcg; unsigned char* wr8; unsigned short* colp;
    int* pacc; unsigned* cntR; unsigned* cntC;
    float* rdeg; float* w;
    unsigned* totR; unsigned* totC; unsigned* baseR; unsigned* baseC;
    unsigned* flags; int* ovf; float* errF;
};
__device__ __forceinline__ P mk(char* ws) {
    P p;
    p.wcg  = (unsigned*)(ws + OFF_WCG);
    p.wr8  = (unsigned char*)(ws + OFF_WR8);
    p.colp = (unsigned short*)(ws + OFF_PACC);     // overlay
    p.pacc = (int*)(ws + OFF_PACC);
    p.cntR = (unsigned*)(ws + OFF_CNTR);
    p.cntC = (unsigned*)(ws + OFF_CNTC);
    unsigned* ctrl = (unsigned*)(ws + OFF_CTRL);
    p.rdeg = (float*)(ws + OFF_RDEG);
    p.w    = (float*)(ws + OFF_W);
    p.totR = ctrl; p.totC = ctrl + 64; p.baseR = ctrl + 128; p.baseC = ctrl + 200;
    p.flags = ctrl + 280; p.ovf = (int*)(ctrl + 281); p.errF = (float*)(ctrl + 288);
    return p;
}

// ---- atomic fallback (is64 input / ring overflow / small ws). No __shared__. ----
__device__ void atomic_fallback(cg::grid_group& grid, int is64,
                                const int* e32, const long long* e64,
                                int* ai, int* deg, float* rdeg,
                                float* vA, float* vB, float* w,
                                float* err, float* out,
                                int tid, int stride, int th)
{
    for (int i = tid; i < NN; i += stride) { ai[i] = 0; deg[i] = 0; vA[i] = INV_N; }
    grid.sync();
    if (is64) { const long long* cols = e64 + NE;
        for (int e = tid; e < NE; e += stride) atomicAdd(&deg[(int)cols[e]], 1); }
    else      { const int* cols = e32 + NE;
        for (int e = tid; e < NE; e += stride) atomicAdd(&deg[cols[e]], 1); }
    grid.sync();
    for (int i = tid; i < NN; i += stride) rdeg[i] = ALPHA / (float)deg[i];
    grid.sync();
    float* v = vA; float* nv = vB;
    for (int iter = 0; iter < MAX_ITER; ++iter) {
        for (int i = tid; i < NN; i += stride) { w[i] = v[i] * rdeg[i]; ai[i] = 0; }
        grid.sync();
        if (is64) { const long long* rows = e64; const long long* cols = e64 + NE;
            for (int e = tid; e < NE; e += stride)
                atomicAdd(&ai[(int)rows[e]], __float2int_rn(w[(int)cols[e]] * SCALE)); }
        else { const int* rows = e32; const int* cols = e32 + NE;
            for (int e = tid; e < NE; e += stride)
                atomicAdd(&ai[rows[e]], __float2int_rn(w[cols[e]] * SCALE)); }
        grid.sync();
        float pe = 0.0f;
        for (int i = tid; i < NN; i += stride) {
            float x = TELEPORT + (float)ai[i] * INVSCALE;
            pe += fabsf(x - v[i]); nv[i] = x;
        }
        #pragma unroll
        for (int off = 32; off > 0; off >>= 1) pe += __shfl_down(pe, off, 64);
        if ((th & 63) == 0) unsafeAtomicAdd(&err[iter], pe);
        grid.sync();
        float e = ((volatile float*)err)[iter];
        float* t = v; v = nv; nv = t;
        if (e < THRESH) break;
    }
    for (int i = tid; i < NN; i += stride) out[i] = v[i];
}

// ---------------- K0: flags / control init ----------------
__global__ __launch_bounds__(256) void k0_init(const int* __restrict__ e32, char* ws)
{
    P p = mk(ws);
    __shared__ int snz;
    const int th = threadIdx.x;
    if (th == 0) snz = 0;
    __syncthreads();
    if (e32[2 * th + 1] != 0) atomicOr(&snz, 1);   // int64 => high words all 0
    __syncthreads();
    if (th == 0) { p.flags[0] = (snz == 0) ? 1u : 0u; *p.ovf = 0; p.w[NN] = 0.0f; }
    if (th < MAX_ITER) p.errF[th] = 0.0f;
}

// ---------------- K1: per-chunk bucket histograms (rows + cols, LDS only) ----------------
__global__ __launch_bounds__(256, 8) void k1_hist(const int* __restrict__ e32, char* ws)
{
    P p = mk(ws);
    if (p.flags[0]) return;
    __shared__ int h[128];
    const int th = threadIdx.x, blk = blockIdx.x;
    const int e0 = (int)(((long long)NE * blk) >> 11);
    const int e1 = (int)(((long long)NE * (blk + 1)) >> 11);
    if (th < 128) h[th] = 0;
    __syncthreads();
    const vi4* R4 = (const vi4*)e32;
    const vi4* C4 = (const vi4*)(e32 + NE);
    const int qe = (e1 + 3) >> 2;
    for (int q = (e0 >> 2) + th; q < qe; q += T) {
        vi4 R = R4[q], C = C4[q];                  // plain loads: seed L3 for K3
        int rr[4] = {R.x, R.y, R.z, R.w}, cc[4] = {C.x, C.y, C.z, C.w};
        #pragma unroll
        for (int j = 0; j < 4; ++j) {
            int e = 4 * q + j;
            if (e >= e0 && e < e1) {
                atomicAdd(&h[rr[j] >> BSH], 1);
                atomicAdd(&h[64 + (cc[j] >> BSH)], 1);
            }
        }
    }
    __syncthreads();
    if (th < 64) {
        p.cntR[(size_t)th * NCH + blk] = (unsigned)h[th];
        p.cntC[(size_t)th * NCH + blk] = (unsigned)h[64 + th];
    }
}

// ---------------- K2: per-bucket exclusive scan over 2048 chunks ----------------
__global__ __launch_bounds__(256, 4) void k2_scan(char* ws)
{
    P p = mk(ws);
    if (p.flags[0]) return;
    __shared__ int S[256];
    const int th = threadIdx.x, blk = blockIdx.x;     // 128 blocks
    const int side = blk >> 6, b = blk & 63;
    unsigned* cnt = (side ? p.cntC : p.cntR) + (size_t)b * NCH;
    unsigned v[8]; unsigned s = 0;
    #pragma unroll
    for (int i = 0; i < 8; ++i) { v[i] = cnt[8 * th + i]; s += v[i]; }
    S[th] = (int)s; __syncthreads();
    for (int off = 1; off < 256; off <<= 1) {
        int x = (th >= off) ? S[th - off] : 0;
        __syncthreads(); S[th] += x; __syncthreads();
    }
    unsigned run = (unsigned)S[th] - s;
    #pragma unroll
    for (int i = 0; i < 8; ++i) { unsigned t = v[i]; cnt[8 * th + i] = run; run += t; }
    if (th == 255) (side ? p.totC : p.totR)[b] = run;
}

// ---------------- K2b: padded bases + col pads ----------------
__global__ __launch_bounds__(256) void k2b_bases(char* ws)
{
    P p = mk(ws);
    if (p.flags[0]) return;
    __shared__ int S[128];
    const int th = threadIdx.x;
    unsigned pt = 0;
    if (th < 128) {
        unsigned t = (th < 64) ? p.totR[th] : p.totC[th - 64];
        pt = (t + 7u) & ~7u;
        S[th] = (int)pt;
    }
    __syncthreads();
    for (int off = 1; off < 64; off <<= 1) {
        int x = (th < 128 && (th & 63) >= off) ? S[th - off] : 0;
        __syncthreads(); if (th < 128) S[th] += x; __syncthreads();
    }
    if (th < 64) {
        p.baseR[th] = (unsigned)S[th] - pt;
        if (th == 63) p.baseR[64] = (unsigned)S[63];
    } else if (th < 128) {
        p.baseC[th - 64] = (unsigned)S[th] - pt;
        if (th == 127) p.baseC[64] = (unsigned)S[127];
    }
    __syncthreads();
    if (th < 64) {                                   // col pads (deg corrected in K4b)
        unsigned tot = p.totC[th], bs = p.baseC[th], pp = (tot + 7u) & ~7u;
        for (unsigned i = tot; i < pp; ++i) p.colp[bs + i] = 0;
    }
}

// ---------------- K3ab: FUSED col + row scatter, one edge-stream pass ----------------
// LDS: pcL u16[64][128] (16K) + wcL u32[64][128] (32K) + wr8L u8[64][128] (8K)
// + 6x64 ctrl (1.5K) = 57.5KB -> 2 blocks/CU.
__global__ __launch_bounds__(256, 2) void k3ab_scat(const int* __restrict__ e32, char* ws)
{
    P p = mk(ws);
    if (p.flags[0]) return;
    __shared__ int SH3[14720];
    unsigned short* pcL  = (unsigned short*)SH3;             // [64][128] u16
    int*            wcL  = SH3 + 4096;                       // [64][128] u32
    unsigned char*  wr8L = (unsigned char*)(SH3 + 12288);    // [64][128] u8
    int* cFill = SH3 + 14336; int* cFlsh = SH3 + 14400; int* cWpos = SH3 + 14464;
    int* rFill = SH3 + 14528; int* rFlsh = SH3 + 14592; int* rWpos = SH3 + 14656;
    const int th = threadIdx.x, blk = blockIdx.x;
    if (blk < 64 && th == 0) {                               // row pads
        unsigned tot = p.totR[blk], bs = p.baseR[blk], pt = (tot + 7u) & ~7u;
        for (unsigned i = tot; i < pt; ++i) { p.wcg[bs + i] = (unsigned)NN; p.wr8[bs + i] = 0; }
    }
    if (th < 64) {
        cFill[th] = 0; cFlsh[th] = 0;
        cWpos[th] = (int)(p.baseC[th] + p.cntC[(size_t)th * NCH + blk]);
        rFill[th] = 0; rFlsh[th] = 0;
        rWpos[th] = (int)(p.baseR[th] + p.cntR[(size_t)th * NCH + blk]);
    }
    __syncthreads();
    const int e0 = (int)(((long long)NE * blk) >> 11);
    const int e1 = (int)(((long long)NE * (blk + 1)) >> 11);
    const vi4* R4 = (const vi4*)e32;
    const vi4* C4 = (const vi4*)(e32 + NE);
    const int qs = e0 >> 2, qe = (e1 + 3) >> 2;
    vi4 Rcur = {0,0,0,0}, Ccur = {0,0,0,0};
    if (qs + th < qe) { Rcur = R4[qs + th]; Ccur = C4[qs + th]; }
    for (int qb = qs; qb < qe; qb += T) {
        vi4 Rnext = {0,0,0,0}, Cnext = {0,0,0,0};
        { int qn = qb + T + th; if (qn < qe) { Rnext = R4[qn]; Cnext = C4[qn]; } }
        const int q = qb + th;
        if (q < qe) {
            int rr[4] = {Rcur.x, Rcur.y, Rcur.z, Rcur.w};
            int cc[4] = {Ccur.x, Ccur.y, Ccur.z, Ccur.w};
            #pragma unroll
            for (int j = 0; j < 4; ++j) {
                int e = 4 * q + j;
                if (e >= e0 && e < e1) {
                    int cb = cc[j] >> BSH;                   // col side
                    int ci = atomicAdd(&cFill[cb], 1);
                    pcL[cb * 128 + (ci & 127)] = (unsigned short)(cc[j] & (BKN - 1));
                    int rb = rr[j] >> BSH;                   // row side (packed)
                    int ri = atomicAdd(&rFill[rb], 1);
                    int sl = ri & 127;
                    int rl14 = rr[j] & (BKN - 1);
                    wcL[rb * 128 + sl]  = (cc[j] & 0xFFFFF) | ((rl14 & 0xFFF) << 20);
                    wr8L[rb * 128 + sl] = (unsigned char)(rl14 >> 12);
                }
            }
        }
        __syncthreads();
        const int wv = th >> 6, lane = th & 63;
        for (int k = 0; k < 16; ++k) {
            const int b = wv * 16 + k;
            int ff = cFill[b], fl = cFlsh[b], wp = cWpos[b];
            if (ff - fl > 128) *p.ovf = 1;
            while (ff - fl >= 64) {
                p.colp[wp + lane] = pcL[b * 128 + ((fl + lane) & 127)];
                fl += 64; wp += 64;
            }
            if (lane == 0) { cFlsh[b] = fl; cWpos[b] = wp; }
            ff = rFill[b]; fl = rFlsh[b]; wp = rWpos[b];
            if (ff - fl > 128) *p.ovf = 1;
            while (ff - fl >= 64) {
                p.wcg[wp + lane] = (unsigned)wcL[b * 128 + ((fl + lane) & 127)];
                p.wr8[wp + lane] = wr8L[b * 128 + ((fl + lane) & 127)];
                fl += 64; wp += 64;
            }
            if (lane == 0) { rFlsh[b] = fl; rWpos[b] = wp; }
        }
        __syncthreads();
        Rcur = Rnext; Ccur = Cnext;
    }
    {   // drain both sides
        const int wv = th >> 6, lane = th & 63;
        for (int k = 0; k < 16; ++k) {
            const int b = wv * 16 + k;
            int ff = cFill[b], fl = cFlsh[b], wp = cWpos[b];
            while (ff > fl) {
                int n = min(64, ff - fl);
                if (lane < n) p.colp[wp + lane] = pcL[b * 128 + ((fl + lane) & 127)];
                fl += n; wp += n;
            }
            ff = rFill[b]; fl = rFlsh[b]; wp = rWpos[b];
            while (ff > fl) {
                int n = min(64, ff - fl);
                if (lane < n) {
                    p.wcg[wp + lane] = (unsigned)wcL[b * 128 + ((fl + lane) & 127)];
                    p.wr8[wp + lane] = wr8L[b * 128 + ((fl + lane) & 127)];
                }
                fl += n; wp += n;
            }
        }
    }
}

// ---------------- K4a: 2-sub deg partial histograms (u16, staged in out) ----------------
__global__ __launch_bounds__(256, 2) void k4a_deg(char* ws, float* __restrict__ outp)
{
    P p = mk(ws);
    if (p.flags[0] || *p.ovf) return;
    __shared__ int SH[16384];
    const int th = threadIdx.x, blk = blockIdx.x;            // 124 blocks
    const int b = blk >> 1, sub = blk & 1;
    for (int j = th; j < 16384; j += T) SH[j] = 0;
    __syncthreads();
    const unsigned bs = p.baseC[b], tot = p.totC[b], pt = (tot + 7u) & ~7u;
    const unsigned nq = pt >> 3;
    const unsigned qlo = (nq * (unsigned)sub) >> 1;
    const unsigned qhi = (nq * (unsigned)(sub + 1)) >> 1;
    const vu4* p8 = (const vu4*)p.colp + (bs >> 3);
    for (unsigned q = qlo + th; q < qhi; q += T) {
        vu4 x = ntload(p8 + q);
        atomicAdd(&SH[x.x & 0xFFFFu], 1); atomicAdd(&SH[x.x >> 16], 1);
        atomicAdd(&SH[x.y & 0xFFFFu], 1); atomicAdd(&SH[x.y >> 16], 1);
        atomicAdd(&SH[x.z & 0xFFFFu], 1); atomicAdd(&SH[x.z >> 16], 1);
        atomicAdd(&SH[x.w & 0xFFFFu], 1); atomicAdd(&SH[x.w >> 16], 1);
    }
    __syncthreads();
    unsigned* hp = (unsigned*)((unsigned short*)outp + (size_t)blk * 16384);
    for (int j = th; j < 8192; j += T)
        __builtin_nontemporal_store(
            (unsigned)((SH[2*j] & 0xFFFF) | (SH[2*j+1] << 16)), hp + j);
}

// ---------------- K4b: merge deg partials -> rdeg, w0 ----------------
__global__ __launch_bounds__(256, 8) void k4b_merge(char* ws, const float* __restrict__ outp)
{
    P p = mk(ws);
    if (p.flags[0] || *p.ovf) return;
    const int th = threadIdx.x, blk = blockIdx.x;            // 489 blocks
    const int b = blk >> 3, off = (blk & 7) * 2048;
    const int padC = (int)(((p.totC[b] + 7u) & ~7u) - p.totC[b]);
    const unsigned* h0 = (const unsigned*)((const unsigned short*)outp
                         + (size_t)(2*b) * 16384 + off);
    const unsigned* h1 = (const unsigned*)((const unsigned short*)outp
                         + (size_t)(2*b+1) * 16384 + off);
    for (int g = th; g < 512; g += T) {
        int node = b * BKN + off + 4 * g;
        if (node < NN) {
            unsigned a0 = ntload(h0 + 2*g), a1 = ntload(h0 + 2*g + 1);
            unsigned b0 = ntload(h1 + 2*g), b1 = ntload(h1 + 2*g + 1);
            int d0 = (int)((a0 & 0xFFFFu) + (b0 & 0xFFFFu));
            int d1 = (int)((a0 >> 16) + (b0 >> 16));
            int d2 = (int)((a1 & 0xFFFFu) + (b1 & 0xFFFFu));
            int d3 = (int)((a1 >> 16) + (b1 >> 16));
            if (off == 0 && g == 0) d0 -= padC;              // pad correction
            float r0 = ALPHA / (float)d0;                    // deg==0 -> inf, never gathered
            float r1 = ALPHA / (float)d1;
            float r2 = ALPHA / (float)d2;
            float r3 = ALPHA / (float)d3;
            float4 rr = {r0, r1, r2, r3};
            *(float4*)&p.rdeg[node] = rr;
            float4 ww = {INV_N * r0, INV_N * r1, INV_N * r2, INV_N * r3};
            *(float4*)&p.w[node] = ww;                       // fused iter-0 phase A
        }
    }
}

// gather 8 w values + extract 8 SH indices for one batch (packed decode)
#define GATH8(G, I, CA, CB, H)                                              \
    G##0 = w[(unsigned)CA.x & 0xFFFFFu];                                    \
    G##1 = w[(unsigned)CA.y & 0xFFFFFu];                                    \
    G##2 = w[(unsigned)CA.z & 0xFFFFFu];                                    \
    G##3 = w[(unsigned)CA.w & 0xFFFFFu];                                    \
    G##4 = w[(unsigned)CB.x & 0xFFFFFu];                                    \
    G##5 = w[(unsigned)CB.y & 0xFFFFFu];                                    \
    G##6 = w[(unsigned)CB.z & 0xFFFFFu];                                    \
    G##7 = w[(unsigned)CB.w & 0xFFFFFu];                                    \
    I##0 = ((unsigned)CA.x >> 20) | ((unsigned)( (H)        & 3ull) << 12); \
    I##1 = ((unsigned)CA.y >> 20) | ((unsigned)(((H) >> 8)  & 3ull) << 12); \
    I##2 = ((unsigned)CA.z >> 20) | ((unsigned)(((H) >> 16) & 3ull) << 12); \
    I##3 = ((unsigned)CA.w >> 20) | ((unsigned)(((H) >> 24) & 3ull) << 12); \
    I##4 = ((unsigned)CB.x >> 20) | ((unsigned)(((H) >> 32) & 3ull) << 12); \
    I##5 = ((unsigned)CB.y >> 20) | ((unsigned)(((H) >> 40) & 3ull) << 12); \
    I##6 = ((unsigned)CB.z >> 20) | ((unsigned)(((H) >> 48) & 3ull) << 12); \
    I##7 = ((unsigned)CB.w >> 20) | ((unsigned)(((H) >> 56) & 3ull) << 12);

#define ATOM8(I, G)                                                         \
    atomicAdd(&SH[I##0], __float2int_rn(G##0 * SCALE));                     \
    atomicAdd(&SH[I##1], __float2int_rn(G##1 * SCALE));                     \
    atomicAdd(&SH[I##2], __float2int_rn(G##2 * SCALE));                     \
    atomicAdd(&SH[I##3], __float2int_rn(G##3 * SCALE));                     \
    atomicAdd(&SH[I##4], __float2int_rn(G##4 * SCALE));                     \
    atomicAdd(&SH[I##5], __float2int_rn(G##5 * SCALE));                     \
    atomicAdd(&SH[I##6], __float2int_rn(G##6 * SCALE));                     \
    atomicAdd(&SH[I##7], __float2int_rn(G##7 * SCALE));

// ---------------- shared phase bodies (scatter / merge) ----------------
template<int TT>
__device__ __forceinline__ void scatter_phase(const P& p, int* SH, int th, int blk)
{
    const int b = blk >> 3, sub = blk & 7;
    for (int j = th; j < 16384; j += TT) SH[j] = 0;
    __syncthreads();
    const unsigned bs = p.baseR[b], tot = p.totR[b], pt = (tot + 7u) & ~7u;
    const unsigned nq = pt >> 3;
    const unsigned qlo = (nq * (unsigned)sub) >> 3;
    const unsigned qhi = (nq * (unsigned)(sub + 1)) >> 3;
    const vi4* __restrict__ c8 = (const vi4*)p.wcg + (bs >> 2);
    const unsigned long long* __restrict__ h8 =
        (const unsigned long long*)(p.wr8 + bs);
    const float* __restrict__ w = p.w;

    // 2-deep pipeline, static A/B renaming: vec loads 2 batches ahead,
    // gathers+decode 1 ahead of the LDS atomics.
    unsigned q = qlo + th;
    vi4 caA = {0,0,0,0}, cbA = {0,0,0,0}, caB = {0,0,0,0}, cbB = {0,0,0,0};
    unsigned long long hA = 0, hB = 0;
    float gA0=0,gA1=0,gA2=0,gA3=0,gA4=0,gA5=0,gA6=0,gA7=0;
    float gB0=0,gB1=0,gB2=0,gB3=0,gB4=0,gB5=0,gB6=0,gB7=0;
    unsigned iA0=0,iA1=0,iA2=0,iA3=0,iA4=0,iA5=0,iA6=0,iA7=0;
    unsigned iB0=0,iB1=0,iB2=0,iB3=0,iB4=0,iB5=0,iB6=0,iB7=0;
    if (q < qhi)      { caA = ntload(c8+2*q);      cbA = ntload(c8+2*q+1);      hA = ntload(h8+q); }
    if (q + TT < qhi) { caB = ntload(c8+2*(q+TT)); cbB = ntload(c8+2*(q+TT)+1); hB = ntload(h8+q+TT); }
    if (q < qhi)      { GATH8(gA, iA, caA, cbA, hA) }
    while (q < qhi) {
        if (q + TT < qhi)   { GATH8(gB, iB, caB, cbB, hB) }
        if (q + 2*TT < qhi) { caA = ntload(c8+2*(q+2*TT)); cbA = ntload(c8+2*(q+2*TT)+1); hA = ntload(h8+q+2*TT); }
        ATOM8(iA, gA)
        q += TT;
        if (q >= qhi) break;
        if (q + TT < qhi)   { GATH8(gA, iA, caA, cbA, hA) }
        if (q + 2*TT < qhi) { caB = ntload(c8+2*(q+2*TT)); cbB = ntload(c8+2*(q+2*TT)+1); hB = ntload(h8+q+2*TT); }
        ATOM8(iB, gB)
        q += TT;
    }
    __syncthreads();
    vi4* pa = (vi4*)(p.pacc + (size_t)blk * 16384);
    const vi4* s4 = (const vi4*)SH;
    for (int j = th; j < 4096; j += TT)
        __builtin_nontemporal_store(s4[j], pa + j);
}

__device__ __forceinline__ void merge_phase(const P& p, float* out, int iter,
                                            int th, int blk, float* sred)
{
    float pe = 0.0f;
    const int b = blk >> 3, off = (blk & 7) * 2048;
    for (int g = th; g < 512; g += T) {
        int node = b * BKN + off + 4 * g;
        if (node < NN) {
            vi4 acc = {0, 0, 0, 0};
            #pragma unroll
            for (int qq = 0; qq < 8; ++qq) {
                const vi4* pp = (const vi4*)(p.pacc + (size_t)(b*8+qq)*16384 + off);
                vi4 x = ntload(pp + g);
                acc.x += x.x; acc.y += x.y; acc.z += x.z; acc.w += x.w;
            }
            float x0 = TELEPORT + (float)acc.x * INVSCALE;
            float x1 = TELEPORT + (float)acc.y * INVSCALE;
            float x2 = TELEPORT + (float)acc.z * INVSCALE;
            float x3 = TELEPORT + (float)acc.w * INVSCALE;
            float4 prev;
            if (iter == 0) prev = make_float4(INV_N, INV_N, INV_N, INV_N);
            else           prev = *(const float4*)&out[node];
            pe += fabsf(x0 - prev.x) + fabsf(x1 - prev.y)
                + fabsf(x2 - prev.z) + fabsf(x3 - prev.w);
            float4 nv = {x0, x1, x2, x3};
            *(float4*)&out[node] = nv;                 // v lives in out
            float4 rd = *(const float4*)&p.rdeg[node];
            float4 nw = {x0*rd.x, x1*rd.y, x2*rd.z, x3*rd.w};
            *(float4*)&p.w[node] = nw;                 // fused next phase A
        }
    }
    #pragma unroll
    for (int o2 = 32; o2 > 0; o2 >>= 1) pe += __shfl_down(pe, o2, 64);
    if ((th & 63) == 0) sred[th >> 6] = pe;
    __syncthreads();
    if (th == 0)
        unsafeAtomicAdd(&p.errF[iter], sred[0] + sred[1] + sred[2] + sred[3]);
}

// ---------------- K5a: iteration-0 scatter (plain, 512 threads) ----------------
__global__ __launch_bounds__(512, 2) void k5a_scatter(char* __restrict__ ws)
{
    P p = mk(ws);
    if (p.flags[0] || *p.ovf) return;
    __shared__ int SH[16384];
    scatter_phase<T5>(p, SH, threadIdx.x, blockIdx.x);
}

// ---------------- K5b: iteration-0 merge (plain) ----------------
__global__ __launch_bounds__(256, 4) void k5b_merge(char* __restrict__ ws,
                                                    float* __restrict__ out)
{
    P p = mk(ws);
    if (p.flags[0] || *p.ovf) return;
    __shared__ float sred[4];
    merge_phase(p, out, 0, threadIdx.x, blockIdx.x, sred);
}

// ---------------- K5c: cooperative loop for iterations >= 1 ----------------
__global__ __launch_bounds__(256, 2)
void k5c_iter(const int* __restrict__ e32, const long long* __restrict__ e64,
              char* __restrict__ ws, float* __restrict__ out)
{
    cg::grid_group grid = cg::this_grid();
    P p = mk(ws);
    const int th = threadIdx.x, blk = blockIdx.x;
    const int tid = blk * T + th;
    const int stride = gridDim.x * T;
    __shared__ int SH[16384];
    __shared__ float sred[4];

    if (p.flags[0] || *p.ovf) {
        atomic_fallback(grid, (int)p.flags[0], e32, e64,
                        (int*)ws, (int*)(ws + (size_t)4*1024*1024), p.rdeg,
                        (float*)(ws + (size_t)8*1024*1024),
                        (float*)(ws + (size_t)12*1024*1024),
                        (float*)(ws + (size_t)16*1024*1024),
                        p.errF, out, tid, stride, th);
        return;
    }

    for (int iter = 1; iter < MAX_ITER; ++iter) {
        const float e = ((volatile float*)p.errF)[iter - 1];
        if (e < THRESH) break;                       // converged at prev iter
        if (blk < NSUBB) scatter_phase<T>(p, SH, th, blk);
        grid.sync();
        if (blk < NSLC) merge_phase(p, out, iter, th, blk, sred);
        grid.sync();
    }
}

// ---- emergency fallback kernel (ws too small / occupancy short) ----
__global__ __launch_bounds__(256, 4)
void pagerank_atomic(const int* __restrict__ e32, const long long* __restrict__ e64,
                     int* __restrict__ ai, int* __restrict__ deg,
                     float* __restrict__ rdeg, float* __restrict__ vA,
                     float* __restrict__ vB, float* __restrict__ w,
                     float* __restrict__ err, int* __restrict__ flags,
                     float* __restrict__ out)
{
    cg::grid_group grid = cg::this_grid();
    const int tid = blockIdx.x * blockDim.x + threadIdx.x;
    const int stride = gridDim.x * blockDim.x;
    if (tid < MAX_ITER) err[tid] = 0.0f;
    if (tid == 0) {
        int nz = 0;
        for (int k = 1; k < 512; k += 2) nz |= e32[k];
        flags[0] = (nz == 0) ? 1 : 0;
    }
    grid.sync();
    atomic_fallback(grid, flags[0], e32, e64, ai, deg, rdeg, vA, vB, w, err, out,
                    tid, stride, threadIdx.x);
}

extern "C" void kernel_launch(void* const* d_in, const int* in_sizes, int n_in,
                              void* d_out, int out_size, void* d_ws, size_t ws_size,
                              hipStream_t stream)
{
    (void)n_in; (void)out_size; (void)in_sizes;
    const int*       e32 = (const int*)d_in[1];
    const long long* e64 = (const long long*)d_in[1];
    float* out = (float*)d_out;
    char*  ws  = (char*)d_ws;

    int occ = 0;
    hipOccupancyMaxActiveBlocksPerMultiprocessor(&occ, (const void*)k5c_iter, T, 0);

    if (ws_size >= NEED && occ >= 2) {
        k0_init<<<1,    T, 0, stream>>>(e32, ws);
        k1_hist<<<NCH,  T, 0, stream>>>(e32, ws);
        k2_scan<<<128,  T, 0, stream>>>(ws);
        k2b_bases<<<1,  T, 0, stream>>>(ws);
        k3ab_scat<<<NCH, T, 0, stream>>>(e32, ws);
        k4a_deg<<<NK4A, T, 0, stream>>>(ws, out);
        k4b_merge<<<NSLC, T, 0, stream>>>(ws, out);
        k5a_scatter<<<NSUBB, T5, 0, stream>>>(ws);
        k5b_merge<<<NSLC, T, 0, stream>>>(ws, out);
        void* args[] = { (void*)&e32, (void*)&e64, (void*)&ws, (void*)&out };
        hipLaunchCooperativeKernel((const void*)k5c_iter,
                                   dim3(512), dim3(T), args, 0, stream);
        return;
    }

    // emergency: device-atomic version, small footprint
    const size_t MB = 1024 * 1024;
    int*   ai    = (int*)(ws);
    int*   deg   = (int*)(ws + 4 * MB);
    float* rdeg  = (float*)(ws + 8 * MB);
    float* vA    = (float*)(ws + 12 * MB);
    float* vB    = (float*)(ws + 16 * MB);
    float* w     = (float*)(ws + 20 * MB);
    float* err   = (float*)(ws + 24 * MB);
    int*   flg   = (int*)(ws + 24 * MB + 4096);
    int occ2 = 0;
    hipOccupancyMaxActiveBlocksPerMultiprocessor(&occ2, (const void*)pagerank_atomic, 256, 0);
    if (occ2 < 1) occ2 = 1;
    int grid = occ2 * 256; if (grid > 2048) grid = 2048;
    void* args[] = { (void*)&e32, (void*)&e64, (void*)&ai, (void*)&deg, (void*)&rdeg,
                     (void*)&vA, (void*)&vB, (void*)&w, (void*)&err, (void*)&flg,
                     (void*)&out };
    hipLaunchCooperativeKernel((const void*)pagerank_atomic,
                               dim3(grid), dim3(256), args, 0, stream);
}